// Round 4
// baseline (3012.167 us; speedup 1.0000x reference)
//
#include <hip/hip_runtime.h>
#include <hip/hip_fp16.h>

#define B 256
#define T 128
#define D 76
#define H 128
#define G 512   // 4H
#define H2 256  // 2H

typedef unsigned int uint32;
typedef unsigned short ushort16;

__device__ __forceinline__ float sigm(float x){ return 1.0f/(1.0f+__expf(-x)); }
__device__ __forceinline__ float fast_rcp(float x){ float r; asm volatile("v_rcp_f32 %0, %1" : "=v"(r) : "v"(x)); return r; }
__device__ __forceinline__ float fast_tanh(float x){ return 1.0f - 2.0f*fast_rcp(1.0f + __expf(2.0f*x)); }
__device__ __forceinline__ float bflo(uint32 u){ return __uint_as_float(u<<16); }
__device__ __forceinline__ float bfhi(uint32 u){ return __uint_as_float(u & 0xffff0000u); }
__device__ __forceinline__ ushort16 f2bf(float f){ uint32 u=__float_as_uint(f); return (ushort16)((u + 0x7fffu + ((u>>16)&1u))>>16); }
__device__ __forceinline__ float h2f_lo(uint32 u){ return __half2float(__ushort_as_half((unsigned short)(u & 0xffffu))); }
__device__ __forceinline__ float h2f_hi(uint32 u){ return __half2float(__ushort_as_half((unsigned short)(u >> 16))); }
__device__ __forceinline__ uint32 pk_f16(float a, float b){
  return (uint32)__half_as_ushort(__float2half(a)) | ((uint32)__half_as_ushort(__float2half(b))<<16);
}

// ---------- fused weight transposes (9 segs) ----------
struct PrepArgs {
  const float* src[9];
  float* dst[9];
  int Gn[9]; int R[9]; int C[9];
};
__global__ __launch_bounds__(256) void prep_k(PrepArgs a){
  int seg = blockIdx.x >> 5;
  const float* s=a.src[seg]; float* d=a.dst[seg];
  int R=a.R[seg], C=a.C[seg], tot=a.Gn[seg]*R*C;
  for (int i=(blockIdx.x&31)*256+threadIdx.x; i<tot; i+=32*256){
    int g=i/(R*C); int rc=i-g*(R*C); int r=rc/C, c=rc-r*C;
    d[((size_t)g*C+c)*R + r] = s[i];
  }
}

// ---------- pack Whh (enc+dec) into f16 k-paired uint2: [phase][d][k2][j] ----------
__global__ __launch_bounds__(256) void pack_whh_k(
  const float* __restrict__ eWhh, const float* __restrict__ dWhh,
  uint2* __restrict__ whhpE, uint2* __restrict__ whhpD)
{
  int idx = blockIdx.x*256 + threadIdx.x;      // 65536 total
  int phase = idx >> 15;
  int rem = idx & 32767;
  int d = rem >> 14;
  int k2 = (rem >> 8) & 63;
  int j = rem & 255;
  const float* Wsrc = phase ? dWhh : eWhh;
  size_t base = ((size_t)(d*512 + j))*128 + 2*k2;
  float2 wa = *(const float2*)(Wsrc + base);
  float2 wb = *(const float2*)(Wsrc + base + (size_t)256*128);
  uint2 v; v.x = pk_f16(wa.x, wa.y); v.y = pk_f16(wb.x, wb.y);
  (phase ? whhpD : whhpE)[rem] = v;
}

// ---------- xg = x @ Wih^T + b, f16-packed pairs (j, j+256). shift=1 for decoder ----------
__global__ __launch_bounds__(256) void xg_k(
  const float* __restrict__ x, const float* __restrict__ WihT, const float* __restrict__ bias,
  uint32* __restrict__ xgp, int shift)
{
  int d = blockIdx.x >> 11;
  int blk = blockIdx.x & 2047;
  int b = blk >> 3, t0 = (blk & 7) * 16;
  int tid = threadIdx.x;
  __shared__ float xs[16][D];
  for (int i=tid;i<16*D;i+=256){
    int r=i/D, k=i-r*D, ts=t0+r-shift;
    xs[r][k] = (ts>=0) ? x[((size_t)b*T+ts)*D + k] : 0.f;
  }
  __syncthreads();
  const float* Wi = WihT + (size_t)d*D*G;
  float a0[16], a1[16];
  #pragma unroll
  for(int r=0;r<16;r++){a0[r]=0.f;a1[r]=0.f;}
  for (int k=0;k<D;k++){
    float w0=Wi[(size_t)k*G+tid], w1=Wi[(size_t)k*G+tid+256];
    #pragma unroll
    for(int r=0;r<16;r++){ float v=xs[r][k]; a0[r]+=v*w0; a1[r]+=v*w1; }
  }
  float bb0=bias[d*G+tid], bb1=bias[d*G+tid+256];
  #pragma unroll
  for(int r=0;r<16;r++)
    xgp[((size_t)(d*B + b)*T + (t0+r))*256 + tid] = pk_f16(a0[r]+bb0, a1[r]+bb1);
}

// ---------- recurrence: block=(dir, 2 rows), Whh f16 in LDS, loops all T ----------
template<int ENC>
__global__ __launch_bounds__(256,1) void rec_k(
  const uint32* __restrict__ xgp, const uint2* __restrict__ whhp,
  const float* __restrict__ h0, __half* __restrict__ on16,
  float* __restrict__ h_fin, float* __restrict__ h_state)
{
  int d = blockIdx.x >> 7;
  int b0 = (blockIdx.x & 127) * 2;
  int tid = threadIdx.x;
  __shared__ uint2 wlds[64*256];       // 128 KB
  __shared__ float hs[2][H];
  __shared__ float gl[2][G];
  const uint2* wp = whhp + (size_t)d*16384;
  for (int i=tid;i<16384;i+=256) wlds[i] = wp[i];
  int r_c = tid>>7, hh_c = tid&127;
  if (ENC) hs[r_c][hh_c] = 0.f;
  else     hs[r_c][hh_c] = h0[(size_t)d*B*H + (size_t)(b0+r_c)*H + hh_c];
  float creg = 0.f, hlast = 0.f;
  __syncthreads();
  for (int t=0;t<T;t++){
    int te = ENC ? (d ? (T-1-t) : t) : t;
    uint32 xw0 = xgp[((size_t)(d*B + b0+0)*T + te)*256 + tid];
    uint32 xw1 = xgp[((size_t)(d*B + b0+1)*T + te)*256 + tid];
    float a00=0.f,a01=0.f,a10=0.f,a11=0.f;
    #pragma unroll 8
    for (int k2=0;k2<64;k2++){
      uint2 w = wlds[k2*256 + tid];
      float2 h0v = *(const float2*)&hs[0][2*k2];
      float2 h1v = *(const float2*)&hs[1][2*k2];
      float wl0=h2f_lo(w.x), wh0=h2f_hi(w.x);
      float wl1=h2f_lo(w.y), wh1=h2f_hi(w.y);
      a00 = fmaf(h0v.x, wl0, a00); a00 = fmaf(h0v.y, wh0, a00);
      a01 = fmaf(h0v.x, wl1, a01); a01 = fmaf(h0v.y, wh1, a01);
      a10 = fmaf(h1v.x, wl0, a10); a10 = fmaf(h1v.y, wh0, a10);
      a11 = fmaf(h1v.x, wl1, a11); a11 = fmaf(h1v.y, wh1, a11);
    }
    a00 += h2f_lo(xw0); a01 += h2f_hi(xw0);
    a10 += h2f_lo(xw1); a11 += h2f_hi(xw1);
    gl[0][tid]=a00; gl[0][tid+256]=a01;
    gl[1][tid]=a10; gl[1][tid+256]=a11;
    __syncthreads();
    float ii=sigm(gl[r_c][hh_c]), ff=sigm(gl[r_c][128+hh_c]);
    float gg=fast_tanh(gl[r_c][256+hh_c]), oo=sigm(gl[r_c][384+hh_c]);
    creg = ff*creg + ii*gg;
    float hv = oo*fast_tanh(creg);
    hs[r_c][hh_c] = hv; hlast = hv;
    if (ENC) on16[((size_t)(b0+r_c)*T + te)*H2 + d*H + hh_c] = __float2half(hv);
    else     h_state[(size_t)(t+1)*2*B*H + (size_t)d*B*H + (size_t)(b0+r_c)*H + hh_c] = hv;
    __syncthreads();
  }
  if (ENC) h_fin[(size_t)d*B*H + (size_t)(b0+r_c)*H + hh_c] = hlast;
}

// ---------- z = mu + eps*exp(0.5 lv) -> h_state[0] ----------
__global__ __launch_bounds__(128) void z_k(
  const float* __restrict__ h_fin, const float* __restrict__ WzmuT, const float* __restrict__ bzmu,
  const float* __restrict__ WzlvT, const float* __restrict__ bzlv, const float* __restrict__ eps_z,
  float* __restrict__ h_state0)
{
  __shared__ float hr[H];
  int d = blockIdx.x >> 8; int b = blockIdx.x & 255;
  int j = threadIdx.x;
  hr[j] = h_fin[(size_t)d*B*H + (size_t)b*H + j];
  __syncthreads();
  float mu=bzmu[j], lv=bzlv[j];
  #pragma unroll 4
  for(int k=0;k<H;k++){ float hv=hr[k]; mu+=hv*WzmuT[k*H+j]; lv+=hv*WzlvT[k*H+j]; }
  size_t idx=(size_t)d*B*H + (size_t)b*H + j;
  h_state0[idx] = mu + eps_z[idx]*__expf(0.5f*lv);
}

// ---------- fused on_s (bf16) + eb = exp(2*(on_s@W2T+b2)) f32 ----------
__global__ __launch_bounds__(256) void onsw2v_k(
  const uint32* __restrict__ on32, const float* __restrict__ WomuT, const float* __restrict__ bomu,
  const float* __restrict__ WolvT, const float* __restrict__ bolv, const float* __restrict__ eps_on,
  const float* __restrict__ W2T, const float* __restrict__ b2,
  ushort16* __restrict__ onsb, float* __restrict__ ebg)
{
  __shared__ float tile[16][H2];
  __shared__ float t2[16][H2];
  size_t row0=(size_t)blockIdx.x*16;
  int tid=threadIdx.x;
  for(int i=tid;i<16*128;i+=256){
    uint32 u = on32[row0*128 + i];
    int r=i>>7, c2=i&127;
    tile[r][2*c2]=h2f_lo(u); tile[r][2*c2+1]=h2f_hi(u);
  }
  __syncthreads();
  float am[16], al[16];
  #pragma unroll
  for(int r=0;r<16;r++){am[r]=0.f;al[r]=0.f;}
  for(int k=0;k<H2;k++){
    float wm=WomuT[k*H2+tid], wl=WolvT[k*H2+tid];
    #pragma unroll
    for(int r=0;r<16;r++){ float v=tile[r][k]; am[r]+=v*wm; al[r]+=v*wl; }
  }
  float bm=bomu[tid], bl=bolv[tid];
  #pragma unroll
  for(int r=0;r<16;r++){
    size_t row=row0+r;
    float v = am[r]+bm + eps_on[row*H2+tid]*__expf(0.5f*(al[r]+bl));
    t2[r][tid]=v;
    onsb[row*H2+tid]=f2bf(v);
  }
  __syncthreads();
  float ac[16];
  #pragma unroll
  for(int r=0;r<16;r++) ac[r]=0.f;
  for(int k=0;k<H2;k++){
    float w=W2T[k*H2+tid];
    #pragma unroll
    for(int r=0;r<16;r++) ac[r]+=t2[r][k]*w;
  }
  float bb=b2[tid];
  #pragma unroll
  for(int r=0;r<16;r++) ebg[(row0+r)*H2+tid]=__expf(2.0f*(ac[r]+bb));
}

// ---------- eq = exp(2*(concat(h0,h1)@W1T+b1)), all (b,t), f32 out ----------
__global__ __launch_bounds__(256) void qp_all_k(
  const float* __restrict__ h_state, const float* __restrict__ W1T, const float* __restrict__ b1,
  float* __restrict__ eqg)
{
  int m0 = blockIdx.x*16; int b = m0>>7; int t0 = m0&127;
  __shared__ float tile[16][H2];
  int tid=threadIdx.x;
  for (int i=tid;i<16*H2;i+=256){
    int r=i>>8, k=i&255; int dd=k>>7, kk=k&127;
    tile[r][k] = h_state[(size_t)(t0+r)*2*B*H + (size_t)dd*B*H + (size_t)b*H + kk];
  }
  __syncthreads();
  float ac[16];
  #pragma unroll
  for(int r=0;r<16;r++) ac[r]=0.f;
  for(int k=0;k<H2;k++){
    float w=W1T[k*H2+tid];
    #pragma unroll
    for(int r=0;r<16;r++) ac[r]+=tile[r][k]*w;
  }
  float bb=b1[tid];
  #pragma unroll
  for(int r=0;r<16;r++) eqg[(size_t)(m0+r)*H2+tid]=__expf(2.0f*(ac[r]+bb));
}

// ---------- attention: block = (b, t-half); eb in registers; score via rcp only ----------
#define SWZ(row,c) ((c) ^ ((row)&31))
__global__ __launch_bounds__(512,4) void attn_k(
  const float* __restrict__ eqg, const float* __restrict__ ebg, const ushort16* __restrict__ onsb,
  const float* __restrict__ att_v, float* __restrict__ ctx)
{
  int b  = blockIdx.x >> 1;
  int t0 = (blockIdx.x & 1) * 64;
  int tid = threadIdx.x;
  int jq = tid & 15, ttb = tid >> 4;          // ttb in [0,32)
  __shared__ uint32 vs[128*128];              // 64 KB swizzled bf16 on_s
  __shared__ __align__(16) float eqs[H2];
  __shared__ __align__(16) float sc[T];
  __shared__ float2 pv2[4][128];
  __shared__ float wsum[2];
  const uint32* vsg = (const uint32*)onsb + (size_t)b*T*128;
  for (int i=tid;i<128*128;i+=512){ int tt=i>>7, c=i&127; vs[tt*128 + SWZ(tt,c)] = vsg[i]; }
  // eb fragments: 4 tt (ttb+32i) x 16 j (jq+16ii) in registers, t-invariant
  float eb0[16], eb1[16], eb2[16], eb3[16], wv[16];
  float vsum_mine = 0.f;
  const float* ebb = ebg + (size_t)b*T*H2;
  #pragma unroll
  for (int ii=0;ii<16;ii++){
    int j = jq + 16*ii;
    eb0[ii] = ebb[(size_t)(ttb    )*H2 + j];
    eb1[ii] = ebb[(size_t)(ttb+32 )*H2 + j];
    eb2[ii] = ebb[(size_t)(ttb+64 )*H2 + j];
    eb3[ii] = ebb[(size_t)(ttb+96 )*H2 + j];
    float v = att_v[j];
    wv[ii] = -2.0f*v;
    vsum_mine += v;
  }
  __syncthreads();
  for (int tq=0; tq<64; tq++){
    int t = t0 + tq;
    if (tid < 64) ((float4*)eqs)[tid] = ((const float4*)(eqg + ((size_t)b*T + t)*H2))[tid];
    __syncthreads();
    float a0=vsum_mine, a1=vsum_mine, a2=vsum_mine, a3=vsum_mine;
    #pragma unroll
    for (int ii=0; ii<16; ii++){
      float eqv = eqs[jq + 16*ii];
      a0 = fmaf(wv[ii], fast_rcp(fmaf(eb0[ii], eqv, 1.f)), a0);
      a1 = fmaf(wv[ii], fast_rcp(fmaf(eb1[ii], eqv, 1.f)), a1);
      a2 = fmaf(wv[ii], fast_rcp(fmaf(eb2[ii], eqv, 1.f)), a2);
      a3 = fmaf(wv[ii], fast_rcp(fmaf(eb3[ii], eqv, 1.f)), a3);
    }
    #pragma unroll
    for (int off=1; off<16; off<<=1){
      a0 += __shfl_xor(a0,off); a1 += __shfl_xor(a1,off);
      a2 += __shfl_xor(a2,off); a3 += __shfl_xor(a3,off);
    }
    if (jq==0){
      sc[ttb]    = __expf(a0);
      sc[ttb+32] = __expf(a1);
      sc[ttb+64] = __expf(a2);
      sc[ttb+96] = __expf(a3);
    }
    __syncthreads();
    if (tid < 128){
      float e = sc[tid];
      #pragma unroll
      for (int off=1; off<64; off<<=1) e += __shfl_xor(e,off);
      if ((tid&63)==0) wsum[tid>>6]=e;
    }
    int jp = tid & 127, q = tid >> 7;
    float p0=0.f, p1=0.f;
    #pragma unroll
    for (int k=0;k<8;k++){
      float4 s4 = ((const float4*)sc)[q*8+k];
      int tt=q*32+k*4;
      uint32 u0 = vs[(tt+0)*128 + SWZ(tt+0,jp)];
      uint32 u1 = vs[(tt+1)*128 + SWZ(tt+1,jp)];
      uint32 u2 = vs[(tt+2)*128 + SWZ(tt+2,jp)];
      uint32 u3 = vs[(tt+3)*128 + SWZ(tt+3,jp)];
      p0 += s4.x*bflo(u0) + s4.y*bflo(u1) + s4.z*bflo(u2) + s4.w*bflo(u3);
      p1 += s4.x*bfhi(u0) + s4.y*bfhi(u1) + s4.z*bfhi(u2) + s4.w*bfhi(u3);
    }
    pv2[q][jp] = make_float2(p0,p1);
    __syncthreads();
    if (tid < H2){
      int jp2 = tid>>1, odd = tid&1;
      float2 r0=pv2[0][jp2], r1=pv2[1][jp2], r2=pv2[2][jp2], r3=pv2[3][jp2];
      float r = odd ? (r0.y+r1.y+r2.y+r3.y) : (r0.x+r1.x+r2.x+r3.x);
      float inv = fast_rcp((wsum[0]+wsum[1])*128.0f);
      ctx[((size_t)b*T+t)*H2 + tid] = r*inv;
    }
    __syncthreads();
  }
}

// ---------- output projection, all (b,t) ----------
__global__ __launch_bounds__(256) void outproj_k(
  const float* __restrict__ h_state, const float* __restrict__ ctx,
  const float* __restrict__ WoutT, const float* __restrict__ bout, float* __restrict__ out)
{
  int m0 = blockIdx.x*16; int b = m0>>7; int t0 = m0&127;
  __shared__ float rb[16][G];
  int tid=threadIdx.x;
  for (int i=tid;i<16*G;i+=256){
    int r=i>>9, c=i&511;
    int t = t0+r;
    float v;
    if (c<H)       v = h_state[(size_t)(t+1)*2*B*H + (size_t)b*H + c];
    else if (c<H2) v = h_state[(size_t)(t+1)*2*B*H + (size_t)B*H + (size_t)b*H + (c-H)];
    else           v = ctx[((size_t)(m0+r))*H2 + (c-H2)];
    rb[r][c]=v;
  }
  __syncthreads();
  for (int o=tid;o<16*D;o+=256){
    int r=o/D, j=o-r*D;
    float acc=bout[j];
    #pragma unroll 4
    for (int k=0;k<G;k++) acc += rb[r][k]*WoutT[k*D+j];
    out[((size_t)(m0+r))*D + j]=acc;
  }
}

extern "C" void kernel_launch(void* const* d_in, const int* in_sizes, int n_in,
                              void* d_out, int out_size, void* d_ws, size_t ws_size,
                              hipStream_t stream) {
  const float* x      =(const float*)d_in[0];
  const float* eps_z  =(const float*)d_in[1];
  const float* eps_on =(const float*)d_in[2];
  const float* enc_Wih=(const float*)d_in[3];
  const float* enc_Whh=(const float*)d_in[4];
  const float* enc_b  =(const float*)d_in[5];
  const float* dec_Wih=(const float*)d_in[6];
  const float* dec_Whh=(const float*)d_in[7];
  const float* dec_b  =(const float*)d_in[8];
  const float* Wzmu=(const float*)d_in[9];  const float* bzmu=(const float*)d_in[10];
  const float* Wzlv=(const float*)d_in[11]; const float* bzlv=(const float*)d_in[12];
  const float* Womu=(const float*)d_in[13]; const float* bomu=(const float*)d_in[14];
  const float* Wolv=(const float*)d_in[15]; const float* bolv=(const float*)d_in[16];
  const float* att_v=(const float*)d_in[17];
  const float* att_W1=(const float*)d_in[18]; const float* att_b1=(const float*)d_in[19];
  const float* att_W2=(const float*)d_in[20]; const float* att_b2=(const float*)d_in[21];
  const float* Wout=(const float*)d_in[22];  const float* bout=(const float*)d_in[23];
  float* out=(float*)d_out;
  float* ws=(float*)d_ws;
  (void)ws_size; (void)n_in; (void)in_sizes; (void)out_size;

  size_t o=0;
  float* encWihT=ws+o; o+=2*D*G;
  float* decWihT=ws+o; o+=2*D*G;
  float* WzmuT=ws+o; o+=H*H;
  float* WzlvT=ws+o; o+=H*H;
  float* WomuT=ws+o; o+=H2*H2;
  float* WolvT=ws+o; o+=H2*H2;
  float* W1T  =ws+o; o+=H2*H2;
  float* W2T  =ws+o; o+=H2*H2;
  float* WoutT=ws+o; o+=G*D;
  uint2* whhpE=(uint2*)(ws+o); o+=65536;
  uint2* whhpD=(uint2*)(ws+o); o+=65536;
  float* h_fin=ws+o; o+=2*B*H;
  __half* on16=(__half*)(ws+o); o+=(size_t)B*T*H2/2;
  float* h_state=ws+o; o+=(size_t)(T+1)*2*B*H;
  float* Abase=ws+o; o+=16777216;                // 64MB: xgE -> xgD -> {eqg 32MB | ctx 32MB}
  float* Cbase=ws+o; o+=12582912;                // 48MB: onsb 16MB + ebg 32MB

  uint32* xgp = (uint32*)Abase;
  float* eqg  = Abase;
  float* ctx  = Abase + 8388608;
  ushort16* onsb = (ushort16*)Cbase;
  float* ebg  = Cbase + 4194304;

  PrepArgs pa;
  const float* srcs[9]={enc_Wih,dec_Wih,Wzmu,Wzlv,Womu,Wolv,att_W1,att_W2,Wout};
  float* dsts[9]={encWihT,decWihT,WzmuT,WzlvT,WomuT,WolvT,W1T,W2T,WoutT};
  int Gns[9]={2,2,1,1,1,1,1,1,1};
  int Rs[9]={G,G,H,H,H2,H2,H2,H2,D};
  int Cs[9]={D,D,H,H,H2,H2,H2,H2,G};
  for(int i=0;i<9;i++){pa.src[i]=srcs[i];pa.dst[i]=dsts[i];pa.Gn[i]=Gns[i];pa.R[i]=Rs[i];pa.C[i]=Cs[i];}
  prep_k<<<288,256,0,stream>>>(pa);
  pack_whh_k<<<256,256,0,stream>>>(enc_Whh, dec_Whh, whhpE, whhpD);

  // encoder phase
  xg_k<<<4096,256,0,stream>>>(x, encWihT, enc_b, xgp, 0);
  rec_k<1><<<256,256,0,stream>>>(xgp, whhpE, nullptr, on16, h_fin, nullptr);
  z_k<<<512,128,0,stream>>>(h_fin, WzmuT,bzmu,WzlvT,bzlv,eps_z, h_state);
  onsw2v_k<<<2048,256,0,stream>>>((const uint32*)on16,WomuT,bomu,WolvT,bolv,eps_on,W2T,att_b2,onsb,ebg);

  // decoder phase (xg reuses region A)
  xg_k<<<4096,256,0,stream>>>(x, decWihT, dec_b, xgp, 1);
  rec_k<0><<<256,256,0,stream>>>(xgp, whhpD, h_state, nullptr, nullptr, h_state);

  qp_all_k<<<2048,256,0,stream>>>(h_state, W1T, att_b1, eqg);
  attn_k<<<512,512,0,stream>>>(eqg, ebg, onsb, att_v, ctx);
  outproj_k<<<2048,256,0,stream>>>(h_state, ctx, WoutT, bout, out);
}

// Round 5
// 1690.892 us; speedup vs baseline: 1.7814x; 1.7814x over previous
//
#include <hip/hip_runtime.h>
#include <hip/hip_fp16.h>

#define B 256
#define T 128
#define D 76
#define H 128
#define G 512   // 4H
#define H2 256  // 2H

typedef unsigned int uint32;
typedef unsigned short ushort16;

__device__ __forceinline__ float sigm(float x){ return 1.0f/(1.0f+__expf(-x)); }
__device__ __forceinline__ float fast_rcp(float x){ float r; asm volatile("v_rcp_f32 %0, %1" : "=v"(r) : "v"(x)); return r; }
__device__ __forceinline__ float fast_tanh(float x){ return 1.0f - 2.0f*fast_rcp(1.0f + __expf(2.0f*x)); }
__device__ __forceinline__ float bflo(uint32 u){ return __uint_as_float(u<<16); }
__device__ __forceinline__ float bfhi(uint32 u){ return __uint_as_float(u & 0xffff0000u); }
__device__ __forceinline__ ushort16 f2bf(float f){ uint32 u=__float_as_uint(f); return (ushort16)((u + 0x7fffu + ((u>>16)&1u))>>16); }
__device__ __forceinline__ float h2f_lo(uint32 u){ return __half2float(__ushort_as_half((unsigned short)(u & 0xffffu))); }
__device__ __forceinline__ float h2f_hi(uint32 u){ return __half2float(__ushort_as_half((unsigned short)(u >> 16))); }
__device__ __forceinline__ uint32 pk_f16(float a, float b){
  return (uint32)__half_as_ushort(__float2half(a)) | ((uint32)__half_as_ushort(__float2half(b))<<16);
}

// ---------- fused weight transposes (9 segs) ----------
struct PrepArgs {
  const float* src[9];
  float* dst[9];
  int Gn[9]; int R[9]; int C[9];
};
__global__ __launch_bounds__(256) void prep_k(PrepArgs a){
  int seg = blockIdx.x >> 5;
  const float* s=a.src[seg]; float* d=a.dst[seg];
  int R=a.R[seg], C=a.C[seg], tot=a.Gn[seg]*R*C;
  for (int i=(blockIdx.x&31)*256+threadIdx.x; i<tot; i+=32*256){
    int g=i/(R*C); int rc=i-g*(R*C); int r=rc/C, c=rc-r*C;
    d[((size_t)g*C+c)*R + r] = s[i];
  }
}

// ---------- pack Whh (enc+dec) into f16 k-paired uint2: [phase][d][k2][j] ----------
__global__ __launch_bounds__(256) void pack_whh_k(
  const float* __restrict__ eWhh, const float* __restrict__ dWhh,
  uint2* __restrict__ whhpE, uint2* __restrict__ whhpD)
{
  int idx = blockIdx.x*256 + threadIdx.x;      // 65536 total
  int phase = idx >> 15;
  int rem = idx & 32767;
  int d = rem >> 14;
  int k2 = (rem >> 8) & 63;
  int j = rem & 255;
  const float* Wsrc = phase ? dWhh : eWhh;
  size_t base = ((size_t)(d*512 + j))*128 + 2*k2;
  float2 wa = *(const float2*)(Wsrc + base);
  float2 wb = *(const float2*)(Wsrc + base + (size_t)256*128);
  uint2 v; v.x = pk_f16(wa.x, wa.y); v.y = pk_f16(wb.x, wb.y);
  (phase ? whhpD : whhpE)[rem] = v;
}

// ---------- xg = x @ Wih^T + b, f16-packed pairs (j, j+256). shift=1 for decoder ----------
__global__ __launch_bounds__(256) void xg_k(
  const float* __restrict__ x, const float* __restrict__ WihT, const float* __restrict__ bias,
  uint32* __restrict__ xgp, int shift)
{
  int d = blockIdx.x >> 11;
  int blk = blockIdx.x & 2047;
  int b = blk >> 3, t0 = (blk & 7) * 16;
  int tid = threadIdx.x;
  __shared__ float xs[16][D];
  for (int i=tid;i<16*D;i+=256){
    int r=i/D, k=i-r*D, ts=t0+r-shift;
    xs[r][k] = (ts>=0) ? x[((size_t)b*T+ts)*D + k] : 0.f;
  }
  __syncthreads();
  const float* Wi = WihT + (size_t)d*D*G;
  float a0[16], a1[16];
  #pragma unroll
  for(int r=0;r<16;r++){a0[r]=0.f;a1[r]=0.f;}
  for (int k=0;k<D;k++){
    float w0=Wi[(size_t)k*G+tid], w1=Wi[(size_t)k*G+tid+256];
    #pragma unroll
    for(int r=0;r<16;r++){ float v=xs[r][k]; a0[r]+=v*w0; a1[r]+=v*w1; }
  }
  float bb0=bias[d*G+tid], bb1=bias[d*G+tid+256];
  #pragma unroll
  for(int r=0;r<16;r++)
    xgp[((size_t)(d*B + b)*T + (t0+r))*256 + tid] = pk_f16(a0[r]+bb0, a1[r]+bb1);
}

// ---------- recurrence: block=(dir, 2 rows), Whh f16 in LDS, loops all T ----------
template<int ENC>
__global__ __launch_bounds__(256,1) void rec_k(
  const uint32* __restrict__ xgp, const uint2* __restrict__ whhp,
  const float* __restrict__ h0, __half* __restrict__ on16,
  float* __restrict__ h_fin, float* __restrict__ h_state)
{
  int d = blockIdx.x >> 7;
  int b0 = (blockIdx.x & 127) * 2;
  int tid = threadIdx.x;
  __shared__ uint2 wlds[64*256];       // 128 KB
  __shared__ float hs[2][H];
  __shared__ float gl[2][G];
  const uint2* wp = whhp + (size_t)d*16384;
  for (int i=tid;i<16384;i+=256) wlds[i] = wp[i];
  int r_c = tid>>7, hh_c = tid&127;
  if (ENC) hs[r_c][hh_c] = 0.f;
  else     hs[r_c][hh_c] = h0[(size_t)d*B*H + (size_t)(b0+r_c)*H + hh_c];
  float creg = 0.f, hlast = 0.f;
  __syncthreads();
  for (int t=0;t<T;t++){
    int te = ENC ? (d ? (T-1-t) : t) : t;
    uint32 xw0 = xgp[((size_t)(d*B + b0+0)*T + te)*256 + tid];
    uint32 xw1 = xgp[((size_t)(d*B + b0+1)*T + te)*256 + tid];
    float a00=0.f,a01=0.f,a10=0.f,a11=0.f;
    #pragma unroll 8
    for (int k2=0;k2<64;k2++){
      uint2 w = wlds[k2*256 + tid];
      float2 h0v = *(const float2*)&hs[0][2*k2];
      float2 h1v = *(const float2*)&hs[1][2*k2];
      float wl0=h2f_lo(w.x), wh0=h2f_hi(w.x);
      float wl1=h2f_lo(w.y), wh1=h2f_hi(w.y);
      a00 = fmaf(h0v.x, wl0, a00); a00 = fmaf(h0v.y, wh0, a00);
      a01 = fmaf(h0v.x, wl1, a01); a01 = fmaf(h0v.y, wh1, a01);
      a10 = fmaf(h1v.x, wl0, a10); a10 = fmaf(h1v.y, wh0, a10);
      a11 = fmaf(h1v.x, wl1, a11); a11 = fmaf(h1v.y, wh1, a11);
    }
    a00 += h2f_lo(xw0); a01 += h2f_hi(xw0);
    a10 += h2f_lo(xw1); a11 += h2f_hi(xw1);
    gl[0][tid]=a00; gl[0][tid+256]=a01;
    gl[1][tid]=a10; gl[1][tid+256]=a11;
    __syncthreads();
    float ii=sigm(gl[r_c][hh_c]), ff=sigm(gl[r_c][128+hh_c]);
    float gg=fast_tanh(gl[r_c][256+hh_c]), oo=sigm(gl[r_c][384+hh_c]);
    creg = ff*creg + ii*gg;
    float hv = oo*fast_tanh(creg);
    hs[r_c][hh_c] = hv; hlast = hv;
    if (ENC) on16[((size_t)(b0+r_c)*T + te)*H2 + d*H + hh_c] = __float2half(hv);
    else     h_state[(size_t)(t+1)*2*B*H + (size_t)d*B*H + (size_t)(b0+r_c)*H + hh_c] = hv;
    __syncthreads();
  }
  if (ENC) h_fin[(size_t)d*B*H + (size_t)(b0+r_c)*H + hh_c] = hlast;
}

// ---------- z = mu + eps*exp(0.5 lv) -> h_state[0] ----------
__global__ __launch_bounds__(128) void z_k(
  const float* __restrict__ h_fin, const float* __restrict__ WzmuT, const float* __restrict__ bzmu,
  const float* __restrict__ WzlvT, const float* __restrict__ bzlv, const float* __restrict__ eps_z,
  float* __restrict__ h_state0)
{
  __shared__ float hr[H];
  int d = blockIdx.x >> 8; int b = blockIdx.x & 255;
  int j = threadIdx.x;
  hr[j] = h_fin[(size_t)d*B*H + (size_t)b*H + j];
  __syncthreads();
  float mu=bzmu[j], lv=bzlv[j];
  #pragma unroll 4
  for(int k=0;k<H;k++){ float hv=hr[k]; mu+=hv*WzmuT[k*H+j]; lv+=hv*WzlvT[k*H+j]; }
  size_t idx=(size_t)d*B*H + (size_t)b*H + j;
  h_state0[idx] = mu + eps_z[idx]*__expf(0.5f*lv);
}

// ---------- fused on_s (bf16) + eb = exp(2*(on_s@W2T+b2)) f32 ----------
__global__ __launch_bounds__(256) void onsw2v_k(
  const uint32* __restrict__ on32, const float* __restrict__ WomuT, const float* __restrict__ bomu,
  const float* __restrict__ WolvT, const float* __restrict__ bolv, const float* __restrict__ eps_on,
  const float* __restrict__ W2T, const float* __restrict__ b2,
  ushort16* __restrict__ onsb, float* __restrict__ ebg)
{
  __shared__ float tile[16][H2];
  __shared__ float t2[16][H2];
  size_t row0=(size_t)blockIdx.x*16;
  int tid=threadIdx.x;
  for(int i=tid;i<16*128;i+=256){
    uint32 u = on32[row0*128 + i];
    int r=i>>7, c2=i&127;
    tile[r][2*c2]=h2f_lo(u); tile[r][2*c2+1]=h2f_hi(u);
  }
  __syncthreads();
  float am[16], al[16];
  #pragma unroll
  for(int r=0;r<16;r++){am[r]=0.f;al[r]=0.f;}
  for(int k=0;k<H2;k++){
    float wm=WomuT[k*H2+tid], wl=WolvT[k*H2+tid];
    #pragma unroll
    for(int r=0;r<16;r++){ float v=tile[r][k]; am[r]+=v*wm; al[r]+=v*wl; }
  }
  float bm=bomu[tid], bl=bolv[tid];
  #pragma unroll
  for(int r=0;r<16;r++){
    size_t row=row0+r;
    float v = am[r]+bm + eps_on[row*H2+tid]*__expf(0.5f*(al[r]+bl));
    t2[r][tid]=v;
    onsb[row*H2+tid]=f2bf(v);
  }
  __syncthreads();
  float ac[16];
  #pragma unroll
  for(int r=0;r<16;r++) ac[r]=0.f;
  for(int k=0;k<H2;k++){
    float w=W2T[k*H2+tid];
    #pragma unroll
    for(int r=0;r<16;r++) ac[r]+=t2[r][k]*w;
  }
  float bb=b2[tid];
  #pragma unroll
  for(int r=0;r<16;r++) ebg[(row0+r)*H2+tid]=__expf(2.0f*(ac[r]+bb));
}

// ---------- eq = exp(2*(concat(h0,h1)@W1T+b1)), all (b,t), f32 out ----------
__global__ __launch_bounds__(256) void qp_all_k(
  const float* __restrict__ h_state, const float* __restrict__ W1T, const float* __restrict__ b1,
  float* __restrict__ eqg)
{
  int m0 = blockIdx.x*16; int b = m0>>7; int t0 = m0&127;
  __shared__ float tile[16][H2];
  int tid=threadIdx.x;
  for (int i=tid;i<16*H2;i+=256){
    int r=i>>8, k=i&255; int dd=k>>7, kk=k&127;
    tile[r][k] = h_state[(size_t)(t0+r)*2*B*H + (size_t)dd*B*H + (size_t)b*H + kk];
  }
  __syncthreads();
  float ac[16];
  #pragma unroll
  for(int r=0;r<16;r++) ac[r]=0.f;
  for(int k=0;k<H2;k++){
    float w=W1T[k*H2+tid];
    #pragma unroll
    for(int r=0;r<16;r++) ac[r]+=tile[r][k]*w;
  }
  float bb=b1[tid];
  #pragma unroll
  for(int r=0;r<16;r++) eqg[(size_t)(m0+r)*H2+tid]=__expf(2.0f*(ac[r]+bb));
}

// ---------- attention: block = (b, t-half); eb in registers; score via rcp only ----------
// __launch_bounds__(512,2): 2 blocks/CU (LDS-limited anyway); 128 VGPR budget keeps
// the 80-float eb/wv register plan resident. (512,4) forced 64 VGPR -> scratch spill
// -> 2.6 GB/dispatch FETCH (R4 regression).
#define SWZ(row,c) ((c) ^ ((row)&31))
__global__ __launch_bounds__(512,2) void attn_k(
  const float* __restrict__ eqg, const float* __restrict__ ebg, const ushort16* __restrict__ onsb,
  const float* __restrict__ att_v, float* __restrict__ ctx)
{
  int b  = blockIdx.x >> 1;
  int t0 = (blockIdx.x & 1) * 64;
  int tid = threadIdx.x;
  int jq = tid & 15, ttb = tid >> 4;          // ttb in [0,32)
  __shared__ uint32 vs[128*128];              // 64 KB swizzled bf16 on_s
  __shared__ __align__(16) float eqs[H2];
  __shared__ __align__(16) float sc[T];
  __shared__ float2 pv2[4][128];
  __shared__ float wsum[2];
  const uint32* vsg = (const uint32*)onsb + (size_t)b*T*128;
  for (int i=tid;i<128*128;i+=512){ int tt=i>>7, c=i&127; vs[tt*128 + SWZ(tt,c)] = vsg[i]; }
  // eb fragments: 4 tt (ttb+32i) x 16 j (jq+16ii) in registers, t-invariant
  float eb0[16], eb1[16], eb2[16], eb3[16], wv[16];
  float vsum_mine = 0.f;
  const float* ebb = ebg + (size_t)b*T*H2;
  #pragma unroll
  for (int ii=0;ii<16;ii++){
    int j = jq + 16*ii;
    eb0[ii] = ebb[(size_t)(ttb    )*H2 + j];
    eb1[ii] = ebb[(size_t)(ttb+32 )*H2 + j];
    eb2[ii] = ebb[(size_t)(ttb+64 )*H2 + j];
    eb3[ii] = ebb[(size_t)(ttb+96 )*H2 + j];
    float v = att_v[j];
    wv[ii] = -2.0f*v;
    vsum_mine += v;
  }
  __syncthreads();
  for (int tq=0; tq<64; tq++){
    int t = t0 + tq;
    if (tid < 64) ((float4*)eqs)[tid] = ((const float4*)(eqg + ((size_t)b*T + t)*H2))[tid];
    __syncthreads();
    float a0=vsum_mine, a1=vsum_mine, a2=vsum_mine, a3=vsum_mine;
    #pragma unroll
    for (int ii=0; ii<16; ii++){
      float eqv = eqs[jq + 16*ii];
      a0 = fmaf(wv[ii], fast_rcp(fmaf(eb0[ii], eqv, 1.f)), a0);
      a1 = fmaf(wv[ii], fast_rcp(fmaf(eb1[ii], eqv, 1.f)), a1);
      a2 = fmaf(wv[ii], fast_rcp(fmaf(eb2[ii], eqv, 1.f)), a2);
      a3 = fmaf(wv[ii], fast_rcp(fmaf(eb3[ii], eqv, 1.f)), a3);
    }
    #pragma unroll
    for (int off=1; off<16; off<<=1){
      a0 += __shfl_xor(a0,off); a1 += __shfl_xor(a1,off);
      a2 += __shfl_xor(a2,off); a3 += __shfl_xor(a3,off);
    }
    if (jq==0){
      sc[ttb]    = __expf(a0);
      sc[ttb+32] = __expf(a1);
      sc[ttb+64] = __expf(a2);
      sc[ttb+96] = __expf(a3);
    }
    __syncthreads();
    if (tid < 128){
      float e = sc[tid];
      #pragma unroll
      for (int off=1; off<64; off<<=1) e += __shfl_xor(e,off);
      if ((tid&63)==0) wsum[tid>>6]=e;
    }
    int jp = tid & 127, q = tid >> 7;
    float p0=0.f, p1=0.f;
    #pragma unroll
    for (int k=0;k<8;k++){
      float4 s4 = ((const float4*)sc)[q*8+k];
      int tt=q*32+k*4;
      uint32 u0 = vs[(tt+0)*128 + SWZ(tt+0,jp)];
      uint32 u1 = vs[(tt+1)*128 + SWZ(tt+1,jp)];
      uint32 u2 = vs[(tt+2)*128 + SWZ(tt+2,jp)];
      uint32 u3 = vs[(tt+3)*128 + SWZ(tt+3,jp)];
      p0 += s4.x*bflo(u0) + s4.y*bflo(u1) + s4.z*bflo(u2) + s4.w*bflo(u3);
      p1 += s4.x*bfhi(u0) + s4.y*bfhi(u1) + s4.z*bfhi(u2) + s4.w*bfhi(u3);
    }
    pv2[q][jp] = make_float2(p0,p1);
    __syncthreads();
    if (tid < H2){
      int jp2 = tid>>1, odd = tid&1;
      float2 r0=pv2[0][jp2], r1=pv2[1][jp2], r2=pv2[2][jp2], r3=pv2[3][jp2];
      float r = odd ? (r0.y+r1.y+r2.y+r3.y) : (r0.x+r1.x+r2.x+r3.x);
      float inv = fast_rcp((wsum[0]+wsum[1])*128.0f);
      ctx[((size_t)b*T+t)*H2 + tid] = r*inv;
    }
    __syncthreads();
  }
}

// ---------- output projection, all (b,t) ----------
__global__ __launch_bounds__(256) void outproj_k(
  const float* __restrict__ h_state, const float* __restrict__ ctx,
  const float* __restrict__ WoutT, const float* __restrict__ bout, float* __restrict__ out)
{
  int m0 = blockIdx.x*16; int b = m0>>7; int t0 = m0&127;
  __shared__ float rb[16][G];
  int tid=threadIdx.x;
  for (int i=tid;i<16*G;i+=256){
    int r=i>>9, c=i&511;
    int t = t0+r;
    float v;
    if (c<H)       v = h_state[(size_t)(t+1)*2*B*H + (size_t)b*H + c];
    else if (c<H2) v = h_state[(size_t)(t+1)*2*B*H + (size_t)B*H + (size_t)b*H + (c-H)];
    else           v = ctx[((size_t)(m0+r))*H2 + (c-H2)];
    rb[r][c]=v;
  }
  __syncthreads();
  for (int o=tid;o<16*D;o+=256){
    int r=o/D, j=o-r*D;
    float acc=bout[j];
    #pragma unroll 4
    for (int k=0;k<G;k++) acc += rb[r][k]*WoutT[k*D+j];
    out[((size_t)(m0+r))*D + j]=acc;
  }
}

extern "C" void kernel_launch(void* const* d_in, const int* in_sizes, int n_in,
                              void* d_out, int out_size, void* d_ws, size_t ws_size,
                              hipStream_t stream) {
  const float* x      =(const float*)d_in[0];
  const float* eps_z  =(const float*)d_in[1];
  const float* eps_on =(const float*)d_in[2];
  const float* enc_Wih=(const float*)d_in[3];
  const float* enc_Whh=(const float*)d_in[4];
  const float* enc_b  =(const float*)d_in[5];
  const float* dec_Wih=(const float*)d_in[6];
  const float* dec_Whh=(const float*)d_in[7];
  const float* dec_b  =(const float*)d_in[8];
  const float* Wzmu=(const float*)d_in[9];  const float* bzmu=(const float*)d_in[10];
  const float* Wzlv=(const float*)d_in[11]; const float* bzlv=(const float*)d_in[12];
  const float* Womu=(const float*)d_in[13]; const float* bomu=(const float*)d_in[14];
  const float* Wolv=(const float*)d_in[15]; const float* bolv=(const float*)d_in[16];
  const float* att_v=(const float*)d_in[17];
  const float* att_W1=(const float*)d_in[18]; const float* att_b1=(const float*)d_in[19];
  const float* att_W2=(const float*)d_in[20]; const float* att_b2=(const float*)d_in[21];
  const float* Wout=(const float*)d_in[22];  const float* bout=(const float*)d_in[23];
  float* out=(float*)d_out;
  float* ws=(float*)d_ws;
  (void)ws_size; (void)n_in; (void)in_sizes; (void)out_size;

  size_t o=0;
  float* encWihT=ws+o; o+=2*D*G;
  float* decWihT=ws+o; o+=2*D*G;
  float* WzmuT=ws+o; o+=H*H;
  float* WzlvT=ws+o; o+=H*H;
  float* WomuT=ws+o; o+=H2*H2;
  float* WolvT=ws+o; o+=H2*H2;
  float* W1T  =ws+o; o+=H2*H2;
  float* W2T  =ws+o; o+=H2*H2;
  float* WoutT=ws+o; o+=G*D;
  uint2* whhpE=(uint2*)(ws+o); o+=65536;
  uint2* whhpD=(uint2*)(ws+o); o+=65536;
  float* h_fin=ws+o; o+=2*B*H;
  __half* on16=(__half*)(ws+o); o+=(size_t)B*T*H2/2;
  float* h_state=ws+o; o+=(size_t)(T+1)*2*B*H;
  float* Abase=ws+o; o+=16777216;                // 64MB: xgE -> xgD -> {eqg 32MB | ctx 32MB}
  float* Cbase=ws+o; o+=12582912;                // 48MB: onsb 16MB + ebg 32MB

  uint32* xgp = (uint32*)Abase;
  float* eqg  = Abase;
  float* ctx  = Abase + 8388608;
  ushort16* onsb = (ushort16*)Cbase;
  float* ebg  = Cbase + 4194304;

  PrepArgs pa;
  const float* srcs[9]={enc_Wih,dec_Wih,Wzmu,Wzlv,Womu,Wolv,att_W1,att_W2,Wout};
  float* dsts[9]={encWihT,decWihT,WzmuT,WzlvT,WomuT,WolvT,W1T,W2T,WoutT};
  int Gns[9]={2,2,1,1,1,1,1,1,1};
  int Rs[9]={G,G,H,H,H2,H2,H2,H2,D};
  int Cs[9]={D,D,H,H,H2,H2,H2,H2,G};
  for(int i=0;i<9;i++){pa.src[i]=srcs[i];pa.dst[i]=dsts[i];pa.Gn[i]=Gns[i];pa.R[i]=Rs[i];pa.C[i]=Cs[i];}
  prep_k<<<288,256,0,stream>>>(pa);
  pack_whh_k<<<256,256,0,stream>>>(enc_Whh, dec_Whh, whhpE, whhpD);

  // encoder phase
  xg_k<<<4096,256,0,stream>>>(x, encWihT, enc_b, xgp, 0);
  rec_k<1><<<256,256,0,stream>>>(xgp, whhpE, nullptr, on16, h_fin, nullptr);
  z_k<<<512,128,0,stream>>>(h_fin, WzmuT,bzmu,WzlvT,bzlv,eps_z, h_state);
  onsw2v_k<<<2048,256,0,stream>>>((const uint32*)on16,WomuT,bomu,WolvT,bolv,eps_on,W2T,att_b2,onsb,ebg);

  // decoder phase (xg reuses region A)
  xg_k<<<4096,256,0,stream>>>(x, decWihT, dec_b, xgp, 1);
  rec_k<0><<<256,256,0,stream>>>(xgp, whhpD, h_state, nullptr, nullptr, h_state);

  qp_all_k<<<2048,256,0,stream>>>(h_state, W1T, att_b1, eqg);
  attn_k<<<512,512,0,stream>>>(eqg, ebg, onsb, att_v, ctx);
  outproj_k<<<2048,256,0,stream>>>(h_state, ctx, WoutT, bout, out);
}

// Round 6
// 1280.789 us; speedup vs baseline: 2.3518x; 1.3202x over previous
//
#include <hip/hip_runtime.h>
#include <hip/hip_fp16.h>

#define B 256
#define T 128
#define D 76
#define H 128
#define G 512   // 4H
#define H2 256  // 2H

typedef unsigned int uint32;
typedef unsigned short ushort16;
typedef _Float16 h2_t __attribute__((ext_vector_type(2)));

__device__ __forceinline__ float sigm(float x){ return 1.0f/(1.0f+__expf(-x)); }
__device__ __forceinline__ float fast_rcp(float x){ float r; asm volatile("v_rcp_f32 %0, %1" : "=v"(r) : "v"(x)); return r; }
__device__ __forceinline__ float fast_tanh(float x){ return 1.0f - 2.0f*fast_rcp(1.0f + __expf(2.0f*x)); }
__device__ __forceinline__ float bflo(uint32 u){ return __uint_as_float(u<<16); }
__device__ __forceinline__ float bfhi(uint32 u){ return __uint_as_float(u & 0xffff0000u); }
__device__ __forceinline__ ushort16 f2bf(float f){ uint32 u=__float_as_uint(f); return (ushort16)((u + 0x7fffu + ((u>>16)&1u))>>16); }
__device__ __forceinline__ float h2f_lo(uint32 u){ return __half2float(__ushort_as_half((unsigned short)(u & 0xffffu))); }
__device__ __forceinline__ float h2f_hi(uint32 u){ return __half2float(__ushort_as_half((unsigned short)(u >> 16))); }
__device__ __forceinline__ uint32 pk_f16(float a, float b){
  return (uint32)__half_as_ushort(__float2half(a)) | ((uint32)__half_as_ushort(__float2half(b))<<16);
}
__device__ __forceinline__ float dot2(uint32 w, uint32 h, float acc){
  return __builtin_amdgcn_fdot2(__builtin_bit_cast(h2_t, w), __builtin_bit_cast(h2_t, h), acc, false);
}

// ---------- fused weight transposes (9 segs) ----------
struct PrepArgs {
  const float* src[9];
  float* dst[9];
  int Gn[9]; int R[9]; int C[9];
};
__global__ __launch_bounds__(256) void prep_k(PrepArgs a){
  int seg = blockIdx.x >> 5;
  const float* s=a.src[seg]; float* d=a.dst[seg];
  int R=a.R[seg], C=a.C[seg], tot=a.Gn[seg]*R*C;
  for (int i=(blockIdx.x&31)*256+threadIdx.x; i<tot; i+=32*256){
    int g=i/(R*C); int rc=i-g*(R*C); int r=rc/C, c=rc-r*C;
    d[((size_t)g*C+c)*R + r] = s[i];
  }
}

// ---------- pack Whh (enc+dec) f16 k-pairs: wpk[phase][d][k2][j] = (W[d][j][2k2], W[d][j][2k2+1]) ----------
__global__ __launch_bounds__(256) void pack_whh_k(
  const float* __restrict__ eWhh, const float* __restrict__ dWhh,
  uint32* __restrict__ wpkE, uint32* __restrict__ wpkD)
{
  int idx = blockIdx.x*256 + threadIdx.x;      // 131072 total
  int phase = idx >> 16;
  int rem = idx & 65535;
  int d = rem >> 15;
  int k2 = (rem >> 9) & 63;
  int j = rem & 511;
  const float* Wsrc = phase ? dWhh : eWhh;
  float2 wa = *(const float2*)(Wsrc + ((size_t)(d*512 + j))*128 + 2*k2);
  (phase ? wpkD : wpkE)[rem] = pk_f16(wa.x, wa.y);
}

// ---------- xg = x @ Wih^T + b, flat f16 [d][b][t][512]. shift=1 for decoder ----------
__global__ __launch_bounds__(256) void xg_k(
  const float* __restrict__ x, const float* __restrict__ WihT, const float* __restrict__ bias,
  __half* __restrict__ xgh, int shift)
{
  int d = blockIdx.x >> 11;
  int blk = blockIdx.x & 2047;
  int b = blk >> 3, t0 = (blk & 7) * 16;
  int tid = threadIdx.x;
  __shared__ float xs[16][D];
  for (int i=tid;i<16*D;i+=256){
    int r=i/D, k=i-r*D, ts=t0+r-shift;
    xs[r][k] = (ts>=0) ? x[((size_t)b*T+ts)*D + k] : 0.f;
  }
  __syncthreads();
  const float* Wi = WihT + (size_t)d*D*G;
  float a0[16], a1[16];
  #pragma unroll
  for(int r=0;r<16;r++){a0[r]=0.f;a1[r]=0.f;}
  for (int k=0;k<D;k++){
    float w0=Wi[(size_t)k*G+tid], w1=Wi[(size_t)k*G+tid+256];
    #pragma unroll
    for(int r=0;r<16;r++){ float v=xs[r][k]; a0[r]+=v*w0; a1[r]+=v*w1; }
  }
  float bb0=bias[d*G+tid], bb1=bias[d*G+tid+256];
  #pragma unroll
  for(int r=0;r<16;r++){
    size_t row = (size_t)(d*B + b)*T + (t0+r);
    xgh[row*512 + tid]       = __float2half(a0[r]+bb0);
    xgh[row*512 + tid + 256] = __float2half(a1[r]+bb1);
  }
}

// ---------- recurrence: block=(dir,b) 512 thr (thread=gate); weights in 64 VGPRs; dot2 inner ----------
template<int ENC>
__global__ __launch_bounds__(512,2) void rec_k(
  const __half* __restrict__ xgh, const uint32* __restrict__ wpk,
  const float* __restrict__ h0, __half* __restrict__ on16,
  float* __restrict__ h_fin, float* __restrict__ h_state)
{
  int d = blockIdx.x >> 8;
  int b = blockIdx.x & 255;
  int tid = threadIdx.x;               // gate j in [0,512)
  __shared__ float gl[G];
  __shared__ __half hs_h[H];
  // 64 weight pairs for this gate column, resident in VGPRs for all 128 steps
  uint32 wreg[64];
  const uint32* wp = wpk + (size_t)d*64*512;
  #pragma unroll
  for (int k2=0;k2<64;k2++) wreg[k2] = wp[k2*512 + tid];
  if (tid < H){
    float hv = ENC ? 0.f : h0[(size_t)d*B*H + (size_t)b*H + tid];
    hs_h[tid] = __float2half(hv);
  }
  float creg = 0.f, hlast = 0.f;
  const __half* xrow = xgh + (size_t)(d*B + b)*T*512;
  __syncthreads();
  for (int t=0;t<T;t++){
    int te = ENC ? (d ? (T-1-t) : t) : t;
    __half xr = xrow[(size_t)te*512 + tid];        // issued early, used at end
    const uint32* h32 = (const uint32*)hs_h;
    float acc0 = 0.f, acc1 = 0.f;
    #pragma unroll
    for (int k2=0;k2<64;k2+=2){
      acc0 = dot2(wreg[k2],   h32[k2],   acc0);
      acc1 = dot2(wreg[k2+1], h32[k2+1], acc1);
    }
    gl[tid] = acc0 + acc1 + __half2float(xr);
    __syncthreads();
    if (tid < H){
      float ii=sigm(gl[tid]), ff=sigm(gl[128+tid]);
      float gg=fast_tanh(gl[256+tid]), oo=sigm(gl[384+tid]);
      creg = ff*creg + ii*gg;
      float hv = oo*fast_tanh(creg);
      hlast = hv;
      hs_h[tid] = __float2half(hv);
      if (ENC) on16[((size_t)b*T + te)*H2 + d*H + tid] = __float2half(hv);
      else     h_state[(size_t)(t+1)*2*B*H + (size_t)d*B*H + (size_t)b*H + tid] = hv;
    }
    __syncthreads();
  }
  if (ENC && tid < H) h_fin[(size_t)d*B*H + (size_t)b*H + tid] = hlast;
}

// ---------- z = mu + eps*exp(0.5 lv) -> h_state[0] ----------
__global__ __launch_bounds__(128) void z_k(
  const float* __restrict__ h_fin, const float* __restrict__ WzmuT, const float* __restrict__ bzmu,
  const float* __restrict__ WzlvT, const float* __restrict__ bzlv, const float* __restrict__ eps_z,
  float* __restrict__ h_state0)
{
  __shared__ float hr[H];
  int d = blockIdx.x >> 8; int b = blockIdx.x & 255;
  int j = threadIdx.x;
  hr[j] = h_fin[(size_t)d*B*H + (size_t)b*H + j];
  __syncthreads();
  float mu=bzmu[j], lv=bzlv[j];
  #pragma unroll 4
  for(int k=0;k<H;k++){ float hv=hr[k]; mu+=hv*WzmuT[k*H+j]; lv+=hv*WzlvT[k*H+j]; }
  size_t idx=(size_t)d*B*H + (size_t)b*H + j;
  h_state0[idx] = mu + eps_z[idx]*__expf(0.5f*lv);
}

// ---------- fused on_s (bf16) + eb = exp(2*(on_s@W2T+b2)) f32 ----------
__global__ __launch_bounds__(256) void onsw2v_k(
  const uint32* __restrict__ on32, const float* __restrict__ WomuT, const float* __restrict__ bomu,
  const float* __restrict__ WolvT, const float* __restrict__ bolv, const float* __restrict__ eps_on,
  const float* __restrict__ W2T, const float* __restrict__ b2,
  ushort16* __restrict__ onsb, float* __restrict__ ebg)
{
  __shared__ float tile[16][H2];
  __shared__ float t2[16][H2];
  size_t row0=(size_t)blockIdx.x*16;
  int tid=threadIdx.x;
  for(int i=tid;i<16*128;i+=256){
    uint32 u = on32[row0*128 + i];
    int r=i>>7, c2=i&127;
    tile[r][2*c2]=h2f_lo(u); tile[r][2*c2+1]=h2f_hi(u);
  }
  __syncthreads();
  float am[16], al[16];
  #pragma unroll
  for(int r=0;r<16;r++){am[r]=0.f;al[r]=0.f;}
  for(int k=0;k<H2;k++){
    float wm=WomuT[k*H2+tid], wl=WolvT[k*H2+tid];
    #pragma unroll
    for(int r=0;r<16;r++){ float v=tile[r][k]; am[r]+=v*wm; al[r]+=v*wl; }
  }
  float bm=bomu[tid], bl=bolv[tid];
  #pragma unroll
  for(int r=0;r<16;r++){
    size_t row=row0+r;
    float v = am[r]+bm + eps_on[row*H2+tid]*__expf(0.5f*(al[r]+bl));
    t2[r][tid]=v;
    onsb[row*H2+tid]=f2bf(v);
  }
  __syncthreads();
  float ac[16];
  #pragma unroll
  for(int r=0;r<16;r++) ac[r]=0.f;
  for(int k=0;k<H2;k++){
    float w=W2T[k*H2+tid];
    #pragma unroll
    for(int r=0;r<16;r++) ac[r]+=t2[r][k]*w;
  }
  float bb=b2[tid];
  #pragma unroll
  for(int r=0;r<16;r++) ebg[(row0+r)*H2+tid]=__expf(2.0f*(ac[r]+bb));
}

// ---------- eq = exp(2*(concat(h0,h1)@W1T+b1)), all (b,t), f32 out ----------
__global__ __launch_bounds__(256) void qp_all_k(
  const float* __restrict__ h_state, const float* __restrict__ W1T, const float* __restrict__ b1,
  float* __restrict__ eqg)
{
  int m0 = blockIdx.x*16; int b = m0>>7; int t0 = m0&127;
  __shared__ float tile[16][H2];
  int tid=threadIdx.x;
  for (int i=tid;i<16*H2;i+=256){
    int r=i>>8, k=i&255; int dd=k>>7, kk=k&127;
    tile[r][k] = h_state[(size_t)(t0+r)*2*B*H + (size_t)dd*B*H + (size_t)b*H + kk];
  }
  __syncthreads();
  float ac[16];
  #pragma unroll
  for(int r=0;r<16;r++) ac[r]=0.f;
  for(int k=0;k<H2;k++){
    float w=W1T[k*H2+tid];
    #pragma unroll
    for(int r=0;r<16;r++) ac[r]+=tile[r][k]*w;
  }
  float bb=b1[tid];
  #pragma unroll
  for(int r=0;r<16;r++) eqg[(size_t)(m0+r)*H2+tid]=__expf(2.0f*(ac[r]+bb));
}

// ---------- attention: block = (b, t-half); eb in registers; score via rcp only ----------
#define SWZ(row,c) ((c) ^ ((row)&31))
__global__ __launch_bounds__(512,2) void attn_k(
  const float* __restrict__ eqg, const float* __restrict__ ebg, const ushort16* __restrict__ onsb,
  const float* __restrict__ att_v, float* __restrict__ ctx)
{
  int b  = blockIdx.x >> 1;
  int t0 = (blockIdx.x & 1) * 64;
  int tid = threadIdx.x;
  int jq = tid & 15, ttb = tid >> 4;          // ttb in [0,32)
  __shared__ uint32 vs[128*128];              // 64 KB swizzled bf16 on_s
  __shared__ __align__(16) float eqs[H2];
  __shared__ __align__(16) float sc[T];
  __shared__ float2 pv2[4][128];
  __shared__ float wsum[2];
  const uint32* vsg = (const uint32*)onsb + (size_t)b*T*128;
  for (int i=tid;i<128*128;i+=512){ int tt=i>>7, c=i&127; vs[tt*128 + SWZ(tt,c)] = vsg[i]; }
  // eb fragments: 4 tt (ttb+32i) x 16 j (jq+16ii) in registers, t-invariant
  float eb0[16], eb1[16], eb2[16], eb3[16], wv[16];
  float vsum_mine = 0.f;
  const float* ebb = ebg + (size_t)b*T*H2;
  #pragma unroll
  for (int ii=0;ii<16;ii++){
    int j = jq + 16*ii;
    eb0[ii] = ebb[(size_t)(ttb    )*H2 + j];
    eb1[ii] = ebb[(size_t)(ttb+32 )*H2 + j];
    eb2[ii] = ebb[(size_t)(ttb+64 )*H2 + j];
    eb3[ii] = ebb[(size_t)(ttb+96 )*H2 + j];
    float v = att_v[j];
    wv[ii] = -2.0f*v;
    vsum_mine += v;
  }
  __syncthreads();
  for (int tq=0; tq<64; tq++){
    int t = t0 + tq;
    if (tid < 64) ((float4*)eqs)[tid] = ((const float4*)(eqg + ((size_t)b*T + t)*H2))[tid];
    __syncthreads();
    float a0=vsum_mine, a1=vsum_mine, a2=vsum_mine, a3=vsum_mine;
    #pragma unroll
    for (int ii=0; ii<16; ii++){
      float eqv = eqs[jq + 16*ii];
      a0 = fmaf(wv[ii], fast_rcp(fmaf(eb0[ii], eqv, 1.f)), a0);
      a1 = fmaf(wv[ii], fast_rcp(fmaf(eb1[ii], eqv, 1.f)), a1);
      a2 = fmaf(wv[ii], fast_rcp(fmaf(eb2[ii], eqv, 1.f)), a2);
      a3 = fmaf(wv[ii], fast_rcp(fmaf(eb3[ii], eqv, 1.f)), a3);
    }
    #pragma unroll
    for (int off=1; off<16; off<<=1){
      a0 += __shfl_xor(a0,off); a1 += __shfl_xor(a1,off);
      a2 += __shfl_xor(a2,off); a3 += __shfl_xor(a3,off);
    }
    if (jq==0){
      sc[ttb]    = __expf(a0);
      sc[ttb+32] = __expf(a1);
      sc[ttb+64] = __expf(a2);
      sc[ttb+96] = __expf(a3);
    }
    __syncthreads();
    if (tid < 128){
      float e = sc[tid];
      #pragma unroll
      for (int off=1; off<64; off<<=1) e += __shfl_xor(e,off);
      if ((tid&63)==0) wsum[tid>>6]=e;
    }
    int jp = tid & 127, q = tid >> 7;
    float p0=0.f, p1=0.f;
    #pragma unroll
    for (int k=0;k<8;k++){
      float4 s4 = ((const float4*)sc)[q*8+k];
      int tt=q*32+k*4;
      uint32 u0 = vs[(tt+0)*128 + SWZ(tt+0,jp)];
      uint32 u1 = vs[(tt+1)*128 + SWZ(tt+1,jp)];
      uint32 u2 = vs[(tt+2)*128 + SWZ(tt+2,jp)];
      uint32 u3 = vs[(tt+3)*128 + SWZ(tt+3,jp)];
      p0 += s4.x*bflo(u0) + s4.y*bflo(u1) + s4.z*bflo(u2) + s4.w*bflo(u3);
      p1 += s4.x*bfhi(u0) + s4.y*bfhi(u1) + s4.z*bfhi(u2) + s4.w*bfhi(u3);
    }
    pv2[q][jp] = make_float2(p0,p1);
    __syncthreads();
    if (tid < H2){
      int jp2 = tid>>1, odd = tid&1;
      float2 r0=pv2[0][jp2], r1=pv2[1][jp2], r2=pv2[2][jp2], r3=pv2[3][jp2];
      float r = odd ? (r0.y+r1.y+r2.y+r3.y) : (r0.x+r1.x+r2.x+r3.x);
      float inv = fast_rcp((wsum[0]+wsum[1])*128.0f);
      ctx[((size_t)b*T+t)*H2 + tid] = r*inv;
    }
    __syncthreads();
  }
}

// ---------- output projection, all (b,t) ----------
__global__ __launch_bounds__(256) void outproj_k(
  const float* __restrict__ h_state, const float* __restrict__ ctx,
  const float* __restrict__ WoutT, const float* __restrict__ bout, float* __restrict__ out)
{
  int m0 = blockIdx.x*16; int b = m0>>7; int t0 = m0&127;
  __shared__ float rb[16][G];
  int tid=threadIdx.x;
  for (int i=tid;i<16*G;i+=256){
    int r=i>>9, c=i&511;
    int t = t0+r;
    float v;
    if (c<H)       v = h_state[(size_t)(t+1)*2*B*H + (size_t)b*H + c];
    else if (c<H2) v = h_state[(size_t)(t+1)*2*B*H + (size_t)B*H + (size_t)b*H + (c-H)];
    else           v = ctx[((size_t)(m0+r))*H2 + (c-H2)];
    rb[r][c]=v;
  }
  __syncthreads();
  for (int o=tid;o<16*D;o+=256){
    int r=o/D, j=o-r*D;
    float acc=bout[j];
    #pragma unroll 4
    for (int k=0;k<G;k++) acc += rb[r][k]*WoutT[k*D+j];
    out[((size_t)(m0+r))*D + j]=acc;
  }
}

extern "C" void kernel_launch(void* const* d_in, const int* in_sizes, int n_in,
                              void* d_out, int out_size, void* d_ws, size_t ws_size,
                              hipStream_t stream) {
  const float* x      =(const float*)d_in[0];
  const float* eps_z  =(const float*)d_in[1];
  const float* eps_on =(const float*)d_in[2];
  const float* enc_Wih=(const float*)d_in[3];
  const float* enc_Whh=(const float*)d_in[4];
  const float* enc_b  =(const float*)d_in[5];
  const float* dec_Wih=(const float*)d_in[6];
  const float* dec_Whh=(const float*)d_in[7];
  const float* dec_b  =(const float*)d_in[8];
  const float* Wzmu=(const float*)d_in[9];  const float* bzmu=(const float*)d_in[10];
  const float* Wzlv=(const float*)d_in[11]; const float* bzlv=(const float*)d_in[12];
  const float* Womu=(const float*)d_in[13]; const float* bomu=(const float*)d_in[14];
  const float* Wolv=(const float*)d_in[15]; const float* bolv=(const float*)d_in[16];
  const float* att_v=(const float*)d_in[17];
  const float* att_W1=(const float*)d_in[18]; const float* att_b1=(const float*)d_in[19];
  const float* att_W2=(const float*)d_in[20]; const float* att_b2=(const float*)d_in[21];
  const float* Wout=(const float*)d_in[22];  const float* bout=(const float*)d_in[23];
  float* out=(float*)d_out;
  float* ws=(float*)d_ws;
  (void)ws_size; (void)n_in; (void)in_sizes; (void)out_size;

  size_t o=0;
  float* encWihT=ws+o; o+=2*D*G;
  float* decWihT=ws+o; o+=2*D*G;
  float* WzmuT=ws+o; o+=H*H;
  float* WzlvT=ws+o; o+=H*H;
  float* WomuT=ws+o; o+=H2*H2;
  float* WolvT=ws+o; o+=H2*H2;
  float* W1T  =ws+o; o+=H2*H2;
  float* W2T  =ws+o; o+=H2*H2;
  float* WoutT=ws+o; o+=G*D;
  uint32* wpkE=(uint32*)(ws+o); o+=65536;        // [d][k2][j] f16-pairs
  uint32* wpkD=(uint32*)(ws+o); o+=65536;
  float* h_fin=ws+o; o+=2*B*H;
  __half* on16=(__half*)(ws+o); o+=(size_t)B*T*H2/2;
  float* h_state=ws+o; o+=(size_t)(T+1)*2*B*H;
  float* Abase=ws+o; o+=16777216;                // 64MB: xghE -> xghD -> {eqg 32MB | ctx 32MB}
  float* Cbase=ws+o; o+=12582912;                // 48MB: onsb 16MB + ebg 32MB

  __half* xgh = (__half*)Abase;
  float* eqg  = Abase;
  float* ctx  = Abase + 8388608;
  ushort16* onsb = (ushort16*)Cbase;
  float* ebg  = Cbase + 4194304;

  PrepArgs pa;
  const float* srcs[9]={enc_Wih,dec_Wih,Wzmu,Wzlv,Womu,Wolv,att_W1,att_W2,Wout};
  float* dsts[9]={encWihT,decWihT,WzmuT,WzlvT,WomuT,WolvT,W1T,W2T,WoutT};
  int Gns[9]={2,2,1,1,1,1,1,1,1};
  int Rs[9]={G,G,H,H,H2,H2,H2,H2,D};
  int Cs[9]={D,D,H,H,H2,H2,H2,H2,G};
  for(int i=0;i<9;i++){pa.src[i]=srcs[i];pa.dst[i]=dsts[i];pa.Gn[i]=Gns[i];pa.R[i]=Rs[i];pa.C[i]=Cs[i];}
  prep_k<<<288,256,0,stream>>>(pa);
  pack_whh_k<<<512,256,0,stream>>>(enc_Whh, dec_Whh, wpkE, wpkD);

  // encoder phase
  xg_k<<<4096,256,0,stream>>>(x, encWihT, enc_b, xgh, 0);
  rec_k<1><<<512,512,0,stream>>>(xgh, wpkE, nullptr, on16, h_fin, nullptr);
  z_k<<<512,128,0,stream>>>(h_fin, WzmuT,bzmu,WzlvT,bzlv,eps_z, h_state);
  onsw2v_k<<<2048,256,0,stream>>>((const uint32*)on16,WomuT,bomu,WolvT,bolv,eps_on,W2T,att_b2,onsb,ebg);

  // decoder phase (xg reuses region A)
  xg_k<<<4096,256,0,stream>>>(x, decWihT, dec_b, xgh, 1);
  rec_k<0><<<512,512,0,stream>>>(xgh, wpkD, h_state, nullptr, nullptr, h_state);

  qp_all_k<<<2048,256,0,stream>>>(h_state, W1T, att_b1, eqg);
  attn_k<<<512,512,0,stream>>>(eqg, ebg, onsb, att_v, ctx);
  outproj_k<<<2048,256,0,stream>>>(h_state, ctx, WoutT, bout, out);
}

// Round 7
// 1212.862 us; speedup vs baseline: 2.4835x; 1.0560x over previous
//
#include <hip/hip_runtime.h>
#include <hip/hip_fp16.h>

#define B 256
#define T 128
#define D 76
#define H 128
#define G 512   // 4H
#define H2 256  // 2H

typedef unsigned int uint32;
typedef unsigned short ushort16;
typedef _Float16 h2_t __attribute__((ext_vector_type(2)));

__device__ __forceinline__ float sigm(float x){ return 1.0f/(1.0f+__expf(-x)); }
__device__ __forceinline__ float fast_rcp(float x){ float r; asm volatile("v_rcp_f32 %0, %1" : "=v"(r) : "v"(x)); return r; }
__device__ __forceinline__ float fast_tanh(float x){ return 1.0f - 2.0f*fast_rcp(1.0f + __expf(2.0f*x)); }
__device__ __forceinline__ float bflo(uint32 u){ return __uint_as_float(u<<16); }
__device__ __forceinline__ float bfhi(uint32 u){ return __uint_as_float(u & 0xffff0000u); }
__device__ __forceinline__ ushort16 f2bf(float f){ uint32 u=__float_as_uint(f); return (ushort16)((u + 0x7fffu + ((u>>16)&1u))>>16); }
__device__ __forceinline__ float h2f_lo(uint32 u){ return __half2float(__ushort_as_half((unsigned short)(u & 0xffffu))); }
__device__ __forceinline__ float h2f_hi(uint32 u){ return __half2float(__ushort_as_half((unsigned short)(u >> 16))); }
__device__ __forceinline__ uint32 pk_f16(float a, float b){
  return (uint32)__half_as_ushort(__float2half(a)) | ((uint32)__half_as_ushort(__float2half(b))<<16);
}
__device__ __forceinline__ uint32 pk_bf16(float a, float b){
  return (uint32)f2bf(a) | ((uint32)f2bf(b)<<16);
}
__device__ __forceinline__ float dot2(uint32 w, uint32 h, float acc){
  return __builtin_amdgcn_fdot2(__builtin_bit_cast(h2_t, w), __builtin_bit_cast(h2_t, h), acc, false);
}

// ---------- fused weight transposes (9 segs) ----------
struct PrepArgs {
  const float* src[9];
  float* dst[9];
  int Gn[9]; int R[9]; int C[9];
};
__global__ __launch_bounds__(256) void prep_k(PrepArgs a){
  int seg = blockIdx.x >> 5;
  const float* s=a.src[seg]; float* d=a.dst[seg];
  int R=a.R[seg], C=a.C[seg], tot=a.Gn[seg]*R*C;
  for (int i=(blockIdx.x&31)*256+threadIdx.x; i<tot; i+=32*256){
    int g=i/(R*C); int rc=i-g*(R*C); int r=rc/C, c=rc-r*C;
    d[((size_t)g*C+c)*R + r] = s[i];
  }
}

// ---------- pack Whh (enc+dec) f16 k-pairs: wpk[phase][d][k2][j] = (W[d][j][2k2], W[d][j][2k2+1]) ----------
__global__ __launch_bounds__(256) void pack_whh_k(
  const float* __restrict__ eWhh, const float* __restrict__ dWhh,
  uint32* __restrict__ wpkE, uint32* __restrict__ wpkD)
{
  int idx = blockIdx.x*256 + threadIdx.x;      // 131072 total
  int phase = idx >> 16;
  int rem = idx & 65535;
  int d = rem >> 15;
  int k2 = (rem >> 9) & 63;
  int j = rem & 511;
  const float* Wsrc = phase ? dWhh : eWhh;
  float2 wa = *(const float2*)(Wsrc + ((size_t)(d*512 + j))*128 + 2*k2);
  (phase ? wpkD : wpkE)[rem] = pk_f16(wa.x, wa.y);
}

// ---------- xg = x @ Wih^T + b, flat f16 [d][b][t][512]. shift=1 for decoder ----------
__global__ __launch_bounds__(256) void xg_k(
  const float* __restrict__ x, const float* __restrict__ WihT, const float* __restrict__ bias,
  __half* __restrict__ xgh, int shift)
{
  int d = blockIdx.x >> 11;
  int blk = blockIdx.x & 2047;
  int b = blk >> 3, t0 = (blk & 7) * 16;
  int tid = threadIdx.x;
  __shared__ float xs[16][D];
  for (int i=tid;i<16*D;i+=256){
    int r=i/D, k=i-r*D, ts=t0+r-shift;
    xs[r][k] = (ts>=0) ? x[((size_t)b*T+ts)*D + k] : 0.f;
  }
  __syncthreads();
  const float* Wi = WihT + (size_t)d*D*G;
  float a0[16], a1[16];
  #pragma unroll
  for(int r=0;r<16;r++){a0[r]=0.f;a1[r]=0.f;}
  for (int k=0;k<D;k++){
    float w0=Wi[(size_t)k*G+tid], w1=Wi[(size_t)k*G+tid+256];
    #pragma unroll
    for(int r=0;r<16;r++){ float v=xs[r][k]; a0[r]+=v*w0; a1[r]+=v*w1; }
  }
  float bb0=bias[d*G+tid], bb1=bias[d*G+tid+256];
  #pragma unroll
  for(int r=0;r<16;r++){
    size_t row = (size_t)(d*B + b)*T + (t0+r);
    xgh[row*512 + tid]       = __float2half(a0[r]+bb0);
    xgh[row*512 + tid + 256] = __float2half(a1[r]+bb1);
  }
}

// ---------- recurrence: block=(dir,b) 512 thr (thread=gate); weights in 64 VGPRs; dot2 inner ----------
template<int ENC>
__global__ __launch_bounds__(512,2) void rec_k(
  const __half* __restrict__ xgh, const uint32* __restrict__ wpk,
  const float* __restrict__ h0, __half* __restrict__ on16,
  float* __restrict__ h_fin, float* __restrict__ h_state)
{
  int d = blockIdx.x >> 8;
  int b = blockIdx.x & 255;
  int tid = threadIdx.x;               // gate j in [0,512)
  __shared__ float gl[G];
  __shared__ __half hs_h[H];
  uint32 wreg[64];
  const uint32* wp = wpk + (size_t)d*64*512;
  #pragma unroll
  for (int k2=0;k2<64;k2++) wreg[k2] = wp[k2*512 + tid];
  if (tid < H){
    float hv = ENC ? 0.f : h0[(size_t)d*B*H + (size_t)b*H + tid];
    hs_h[tid] = __float2half(hv);
  }
  float creg = 0.f, hlast = 0.f;
  const __half* xrow = xgh + (size_t)(d*B + b)*T*512;
  __syncthreads();
  for (int t=0;t<T;t++){
    int te = ENC ? (d ? (T-1-t) : t) : t;
    __half xr = xrow[(size_t)te*512 + tid];        // issued early, used at end
    const uint32* h32 = (const uint32*)hs_h;
    float acc0 = 0.f, acc1 = 0.f;
    #pragma unroll
    for (int k2=0;k2<64;k2+=2){
      acc0 = dot2(wreg[k2],   h32[k2],   acc0);
      acc1 = dot2(wreg[k2+1], h32[k2+1], acc1);
    }
    gl[tid] = acc0 + acc1 + __half2float(xr);
    __syncthreads();
    if (tid < H){
      float ii=sigm(gl[tid]), ff=sigm(gl[128+tid]);
      float gg=fast_tanh(gl[256+tid]), oo=sigm(gl[384+tid]);
      creg = ff*creg + ii*gg;
      float hv = oo*fast_tanh(creg);
      hlast = hv;
      hs_h[tid] = __float2half(hv);
      if (ENC) on16[((size_t)b*T + te)*H2 + d*H + tid] = __float2half(hv);
      else     h_state[(size_t)(t+1)*2*B*H + (size_t)d*B*H + (size_t)b*H + tid] = hv;
    }
    __syncthreads();
  }
  if (ENC && tid < H) h_fin[(size_t)d*B*H + (size_t)b*H + tid] = hlast;
}

// ---------- z = mu + eps*exp(0.5 lv) -> h_state[0] ----------
__global__ __launch_bounds__(128) void z_k(
  const float* __restrict__ h_fin, const float* __restrict__ WzmuT, const float* __restrict__ bzmu,
  const float* __restrict__ WzlvT, const float* __restrict__ bzlv, const float* __restrict__ eps_z,
  float* __restrict__ h_state0)
{
  __shared__ float hr[H];
  int d = blockIdx.x >> 8; int b = blockIdx.x & 255;
  int j = threadIdx.x;
  hr[j] = h_fin[(size_t)d*B*H + (size_t)b*H + j];
  __syncthreads();
  float mu=bzmu[j], lv=bzlv[j];
  #pragma unroll 4
  for(int k=0;k<H;k++){ float hv=hr[k]; mu+=hv*WzmuT[k*H+j]; lv+=hv*WzlvT[k*H+j]; }
  size_t idx=(size_t)d*B*H + (size_t)b*H + j;
  h_state0[idx] = mu + eps_z[idx]*__expf(0.5f*lv);
}

// ---------- fused on_s (bf16) + eb = exp(2*(on_s@W2T+b2)) f32 ----------
__global__ __launch_bounds__(256) void onsw2v_k(
  const uint32* __restrict__ on32, const float* __restrict__ WomuT, const float* __restrict__ bomu,
  const float* __restrict__ WolvT, const float* __restrict__ bolv, const float* __restrict__ eps_on,
  const float* __restrict__ W2T, const float* __restrict__ b2,
  ushort16* __restrict__ onsb, float* __restrict__ ebg)
{
  __shared__ float tile[16][H2];
  __shared__ float t2[16][H2];
  size_t row0=(size_t)blockIdx.x*16;
  int tid=threadIdx.x;
  for(int i=tid;i<16*128;i+=256){
    uint32 u = on32[row0*128 + i];
    int r=i>>7, c2=i&127;
    tile[r][2*c2]=h2f_lo(u); tile[r][2*c2+1]=h2f_hi(u);
  }
  __syncthreads();
  float am[16], al[16];
  #pragma unroll
  for(int r=0;r<16;r++){am[r]=0.f;al[r]=0.f;}
  for(int k=0;k<H2;k++){
    float wm=WomuT[k*H2+tid], wl=WolvT[k*H2+tid];
    #pragma unroll
    for(int r=0;r<16;r++){ float v=tile[r][k]; am[r]+=v*wm; al[r]+=v*wl; }
  }
  float bm=bomu[tid], bl=bolv[tid];
  #pragma unroll
  for(int r=0;r<16;r++){
    size_t row=row0+r;
    float v = am[r]+bm + eps_on[row*H2+tid]*__expf(0.5f*(al[r]+bl));
    t2[r][tid]=v;
    onsb[row*H2+tid]=f2bf(v);
  }
  __syncthreads();
  float ac[16];
  #pragma unroll
  for(int r=0;r<16;r++) ac[r]=0.f;
  for(int k=0;k<H2;k++){
    float w=W2T[k*H2+tid];
    #pragma unroll
    for(int r=0;r<16;r++) ac[r]+=t2[r][k]*w;
  }
  float bb=b2[tid];
  #pragma unroll
  for(int r=0;r<16;r++) ebg[(row0+r)*H2+tid]=__expf(2.0f*(ac[r]+bb));
}

// ---------- eq = exp(2*(concat(h0,h1)@W1T+b1)), all (b,t), f32 out ----------
__global__ __launch_bounds__(256) void qp_all_k(
  const float* __restrict__ h_state, const float* __restrict__ W1T, const float* __restrict__ b1,
  float* __restrict__ eqg)
{
  int m0 = blockIdx.x*16; int b = m0>>7; int t0 = m0&127;
  __shared__ float tile[16][H2];
  int tid=threadIdx.x;
  for (int i=tid;i<16*H2;i+=256){
    int r=i>>8, k=i&255; int dd=k>>7, kk=k&127;
    tile[r][k] = h_state[(size_t)(t0+r)*2*B*H + (size_t)dd*B*H + (size_t)b*H + kk];
  }
  __syncthreads();
  float ac[16];
  #pragma unroll
  for(int r=0;r<16;r++) ac[r]=0.f;
  for(int k=0;k<H2;k++){
    float w=W1T[k*H2+tid];
    #pragma unroll
    for(int r=0;r<16;r++) ac[r]+=tile[r][k]*w;
  }
  float bb=b1[tid];
  #pragma unroll
  for(int r=0;r<16;r++) eqg[(size_t)(m0+r)*H2+tid]=__expf(2.0f*(ac[r]+bb));
}

// ---------- attention: block = (b, t-half); TQ=2 queries per sync round ----------
// eb held as bf16-packed pairs (32 VGPR); vs linear (PV reads are row-uniform -> conflict-free).
__global__ __launch_bounds__(512,2) void attn_k(
  const float* __restrict__ eqg, const float* __restrict__ ebg, const uint32* __restrict__ ons32,
  const float* __restrict__ att_v, float* __restrict__ ctx)
{
  int b  = blockIdx.x >> 1;
  int t0 = (blockIdx.x & 1) * 64;
  int tid = threadIdx.x;
  int jq = tid & 15, ttb = tid >> 4;          // ttb in [0,32)
  __shared__ uint32 vs[128*128];              // 64 KB linear bf16-pair on_s [tt][c]
  __shared__ __align__(16) float eqs[2*H2];
  __shared__ __align__(16) float sc[2][T];
  __shared__ float2 pv2[2][4][128];
  __shared__ float wsum4[4];
  {
    const uint4* src = (const uint4*)(ons32 + (size_t)b*T*128);
    uint4* dst = (uint4*)vs;
    #pragma unroll
    for (int i=0;i<8;i++) dst[tid + 512*i] = src[tid + 512*i];
  }
  // eb: 4 tt (ttb+32q) x 16 j, packed bf16 (q0,q1) / (q2,q3); t-invariant
  uint32 ebp01[16], ebp23[16];
  float wv[16];
  float vsum_mine = 0.f;
  const float* ebb = ebg + (size_t)b*T*H2;
  #pragma unroll
  for (int ii=0;ii<16;ii++){
    int j = jq + 16*ii;
    float e0 = ebb[(size_t)(ttb    )*H2 + j];
    float e1 = ebb[(size_t)(ttb+32 )*H2 + j];
    float e2 = ebb[(size_t)(ttb+64 )*H2 + j];
    float e3 = ebb[(size_t)(ttb+96 )*H2 + j];
    ebp01[ii] = pk_bf16(e0, e1);
    ebp23[ii] = pk_bf16(e2, e3);
    float v = att_v[j];
    wv[ii] = -2.0f*v;
    vsum_mine += v;
  }
  __syncthreads();
  for (int tq=0; tq<64; tq+=2){
    // stage eq for two queries (512 floats)
    if (tid < 128) ((float4*)eqs)[tid] = ((const float4*)(eqg + ((size_t)b*T + t0+tq)*H2))[tid];
    __syncthreads();
    float a00=vsum_mine,a01=vsum_mine,a02=vsum_mine,a03=vsum_mine;
    float a10=vsum_mine,a11=vsum_mine,a12=vsum_mine,a13=vsum_mine;
    #pragma unroll
    for (int ii=0; ii<16; ii++){
      float e0=bflo(ebp01[ii]), e1=bfhi(ebp01[ii]);
      float e2=bflo(ebp23[ii]), e3=bfhi(ebp23[ii]);
      float q0=eqs[jq+16*ii], q1=eqs[H2+jq+16*ii];
      float w=wv[ii];
      a00 = fmaf(w, fast_rcp(fmaf(e0,q0,1.f)), a00);
      a01 = fmaf(w, fast_rcp(fmaf(e1,q0,1.f)), a01);
      a02 = fmaf(w, fast_rcp(fmaf(e2,q0,1.f)), a02);
      a03 = fmaf(w, fast_rcp(fmaf(e3,q0,1.f)), a03);
      a10 = fmaf(w, fast_rcp(fmaf(e0,q1,1.f)), a10);
      a11 = fmaf(w, fast_rcp(fmaf(e1,q1,1.f)), a11);
      a12 = fmaf(w, fast_rcp(fmaf(e2,q1,1.f)), a12);
      a13 = fmaf(w, fast_rcp(fmaf(e3,q1,1.f)), a13);
    }
    #pragma unroll
    for (int off=1; off<16; off<<=1){
      a00 += __shfl_xor(a00,off); a01 += __shfl_xor(a01,off);
      a02 += __shfl_xor(a02,off); a03 += __shfl_xor(a03,off);
      a10 += __shfl_xor(a10,off); a11 += __shfl_xor(a11,off);
      a12 += __shfl_xor(a12,off); a13 += __shfl_xor(a13,off);
    }
    if (jq==0){
      sc[0][ttb]=__expf(a00); sc[0][ttb+32]=__expf(a01); sc[0][ttb+64]=__expf(a02); sc[0][ttb+96]=__expf(a03);
      sc[1][ttb]=__expf(a10); sc[1][ttb+32]=__expf(a11); sc[1][ttb+64]=__expf(a12); sc[1][ttb+96]=__expf(a13);
    }
    __syncthreads();
    if (tid < 256){
      int row = tid>>7;
      float e = sc[row][tid&127];
      #pragma unroll
      for (int off=1; off<64; off<<=1) e += __shfl_xor(e,off);
      if ((tid&63)==0) wsum4[tid>>6]=e;
    }
    int jp = tid & 127, q = tid >> 7;
    float p00=0.f,p01=0.f,p10=0.f,p11=0.f;
    #pragma unroll
    for (int k=0;k<8;k++){
      int tt=q*32+k*4;
      float4 s0 = ((const float4*)sc[0])[q*8+k];
      float4 s1 = ((const float4*)sc[1])[q*8+k];
      uint32 u0 = vs[(tt+0)*128 + jp];
      uint32 u1 = vs[(tt+1)*128 + jp];
      uint32 u2 = vs[(tt+2)*128 + jp];
      uint32 u3 = vs[(tt+3)*128 + jp];
      float lo0=bflo(u0),hi0=bfhi(u0),lo1=bflo(u1),hi1=bfhi(u1);
      float lo2=bflo(u2),hi2=bfhi(u2),lo3=bflo(u3),hi3=bfhi(u3);
      p00 += s0.x*lo0 + s0.y*lo1 + s0.z*lo2 + s0.w*lo3;
      p01 += s0.x*hi0 + s0.y*hi1 + s0.z*hi2 + s0.w*hi3;
      p10 += s1.x*lo0 + s1.y*lo1 + s1.z*lo2 + s1.w*lo3;
      p11 += s1.x*hi0 + s1.y*hi1 + s1.z*hi2 + s1.w*hi3;
    }
    pv2[0][q][jp] = make_float2(p00,p01);
    pv2[1][q][jp] = make_float2(p10,p11);
    __syncthreads();
    {
      int row = tid>>8, jj = tid&255;
      float2 r0=pv2[row][0][jj>>1], r1=pv2[row][1][jj>>1], r2=pv2[row][2][jj>>1], r3=pv2[row][3][jj>>1];
      float r = (jj&1) ? (r0.y+r1.y+r2.y+r3.y) : (r0.x+r1.x+r2.x+r3.x);
      float tot = row ? (wsum4[2]+wsum4[3]) : (wsum4[0]+wsum4[1]);
      ctx[((size_t)b*T + t0+tq+row)*H2 + jj] = r * fast_rcp(tot*128.0f);
    }
    __syncthreads();
  }
}

// ---------- output projection, all (b,t) ----------
__global__ __launch_bounds__(256) void outproj_k(
  const float* __restrict__ h_state, const float* __restrict__ ctx,
  const float* __restrict__ WoutT, const float* __restrict__ bout, float* __restrict__ out)
{
  int m0 = blockIdx.x*16; int b = m0>>7; int t0 = m0&127;
  __shared__ float rb[16][G];
  int tid=threadIdx.x;
  for (int i=tid;i<16*G;i+=256){
    int r=i>>9, c=i&511;
    int t = t0+r;
    float v;
    if (c<H)       v = h_state[(size_t)(t+1)*2*B*H + (size_t)b*H + c];
    else if (c<H2) v = h_state[(size_t)(t+1)*2*B*H + (size_t)B*H + (size_t)b*H + (c-H)];
    else           v = ctx[((size_t)(m0+r))*H2 + (c-H2)];
    rb[r][c]=v;
  }
  __syncthreads();
  for (int o=tid;o<16*D;o+=256){
    int r=o/D, j=o-r*D;
    float acc=bout[j];
    #pragma unroll 4
    for (int k=0;k<G;k++) acc += rb[r][k]*WoutT[k*D+j];
    out[((size_t)(m0+r))*D + j]=acc;
  }
}

extern "C" void kernel_launch(void* const* d_in, const int* in_sizes, int n_in,
                              void* d_out, int out_size, void* d_ws, size_t ws_size,
                              hipStream_t stream) {
  const float* x      =(const float*)d_in[0];
  const float* eps_z  =(const float*)d_in[1];
  const float* eps_on =(const float*)d_in[2];
  const float* enc_Wih=(const float*)d_in[3];
  const float* enc_Whh=(const float*)d_in[4];
  const float* enc_b  =(const float*)d_in[5];
  const float* dec_Wih=(const float*)d_in[6];
  const float* dec_Whh=(const float*)d_in[7];
  const float* dec_b  =(const float*)d_in[8];
  const float* Wzmu=(const float*)d_in[9];  const float* bzmu=(const float*)d_in[10];
  const float* Wzlv=(const float*)d_in[11]; const float* bzlv=(const float*)d_in[12];
  const float* Womu=(const float*)d_in[13]; const float* bomu=(const float*)d_in[14];
  const float* Wolv=(const float*)d_in[15]; const float* bolv=(const float*)d_in[16];
  const float* att_v=(const float*)d_in[17];
  const float* att_W1=(const float*)d_in[18]; const float* att_b1=(const float*)d_in[19];
  const float* att_W2=(const float*)d_in[20]; const float* att_b2=(const float*)d_in[21];
  const float* Wout=(const float*)d_in[22];  const float* bout=(const float*)d_in[23];
  float* out=(float*)d_out;
  float* ws=(float*)d_ws;
  (void)ws_size; (void)n_in; (void)in_sizes; (void)out_size;

  size_t o=0;
  float* encWihT=ws+o; o+=2*D*G;
  float* decWihT=ws+o; o+=2*D*G;
  float* WzmuT=ws+o; o+=H*H;
  float* WzlvT=ws+o; o+=H*H;
  float* WomuT=ws+o; o+=H2*H2;
  float* WolvT=ws+o; o+=H2*H2;
  float* W1T  =ws+o; o+=H2*H2;
  float* W2T  =ws+o; o+=H2*H2;
  float* WoutT=ws+o; o+=G*D;
  uint32* wpkE=(uint32*)(ws+o); o+=65536;        // [d][k2][j] f16-pairs
  uint32* wpkD=(uint32*)(ws+o); o+=65536;
  float* h_fin=ws+o; o+=2*B*H;
  __half* on16=(__half*)(ws+o); o+=(size_t)B*T*H2/2;
  float* h_state=ws+o; o+=(size_t)(T+1)*2*B*H;
  float* Abase=ws+o; o+=16777216;                // 64MB: xghE -> xghD -> {eqg 32MB | ctx 32MB}
  float* Cbase=ws+o; o+=12582912;                // 48MB: onsb 16MB + ebg 32MB

  __half* xgh = (__half*)Abase;
  float* eqg  = Abase;
  float* ctx  = Abase + 8388608;
  ushort16* onsb = (ushort16*)Cbase;
  float* ebg  = Cbase + 4194304;

  PrepArgs pa;
  const float* srcs[9]={enc_Wih,dec_Wih,Wzmu,Wzlv,Womu,Wolv,att_W1,att_W2,Wout};
  float* dsts[9]={encWihT,decWihT,WzmuT,WzlvT,WomuT,WolvT,W1T,W2T,WoutT};
  int Gns[9]={2,2,1,1,1,1,1,1,1};
  int Rs[9]={G,G,H,H,H2,H2,H2,H2,D};
  int Cs[9]={D,D,H,H,H2,H2,H2,H2,G};
  for(int i=0;i<9;i++){pa.src[i]=srcs[i];pa.dst[i]=dsts[i];pa.Gn[i]=Gns[i];pa.R[i]=Rs[i];pa.C[i]=Cs[i];}
  prep_k<<<288,256,0,stream>>>(pa);
  pack_whh_k<<<512,256,0,stream>>>(enc_Whh, dec_Whh, wpkE, wpkD);

  // encoder phase
  xg_k<<<4096,256,0,stream>>>(x, encWihT, enc_b, xgh, 0);
  rec_k<1><<<512,512,0,stream>>>(xgh, wpkE, nullptr, on16, h_fin, nullptr);
  z_k<<<512,128,0,stream>>>(h_fin, WzmuT,bzmu,WzlvT,bzlv,eps_z, h_state);
  onsw2v_k<<<2048,256,0,stream>>>((const uint32*)on16,WomuT,bomu,WolvT,bolv,eps_on,W2T,att_b2,onsb,ebg);

  // decoder phase (xg reuses region A)
  xg_k<<<4096,256,0,stream>>>(x, decWihT, dec_b, xgh, 1);
  rec_k<0><<<512,512,0,stream>>>(xgh, wpkD, h_state, nullptr, nullptr, h_state);

  qp_all_k<<<2048,256,0,stream>>>(h_state, W1T, att_b1, eqg);
  attn_k<<<512,512,0,stream>>>(eqg, ebg, (const uint32*)onsb, att_v, ctx);
  outproj_k<<<2048,256,0,stream>>>(h_state, ctx, WoutT, bout, out);
}